// Round 7
// baseline (376.353 us; speedup 1.0000x reference)
//
#include <hip/hip_runtime.h>
#include <hip/hip_bf16.h>
#include <stdint.h>

// Attention layer, MI355X. RoPE is a no-op, mask is exactly causal.
// cvt fp32->bf16 (scale*log2e folded into wq); fused QKV GEMM (V written
// transposed) at the proven R4 structure (128x128, BK=64, single-buffer,
// 2 blocks/CU); causal flash attention with contiguous 128-row q-blocks,
// KV-SPLIT load balance (qt>=8 tiles run as two kv-halves writing additive
// f32 partials; attn_combine normalizes; max serial depth 16, 768 blocks)
// and R7: DOUBLE-BUFFERED K/V staging with counted vmcnt(8) -- the wait
// covers loads issued one full iteration earlier, so per-iter stage latency
// (the R5-profiled 11% MfmaUtil / 5.6% HBM latency-bound gap) is hidden.
// 80KB LDS -> 2 blocks/CU. Out-proj GEMM same R4 structure.

namespace {

constexpr int kB = 2;
constexpr int kS = 2048;
constexpr int kD = 2048;
constexpr int kH = 16;
constexpr int kHD = 128;
constexpr int kM = kB * kS;  // 4096 token rows

typedef __attribute__((ext_vector_type(8))) __bf16 bf16x8;
typedef __attribute__((ext_vector_type(4))) float f32x4;

__device__ __forceinline__ unsigned short f2bf(float x) {
  uint32_t u = __float_as_uint(x);
  u += 0x7fffu + ((u >> 16) & 1u);
  return (unsigned short)(u >> 16);
}

__device__ __forceinline__ void gld_lds16(const void* g, void* l) {
  __builtin_amdgcn_global_load_lds((__attribute__((address_space(1))) void*)g,
                                   (__attribute__((address_space(3))) void*)l,
                                   16, 0, 0);
}

// ---------------- all fp32 -> bf16 casts, one dispatch ----------------
__global__ void cvt_all(const float* __restrict__ x, const float* __restrict__ wq,
                        const float* __restrict__ wk, const float* __restrict__ wv,
                        const float* __restrict__ wo, unsigned short* __restrict__ xb,
                        unsigned short* __restrict__ wqkv) {
  constexpr int n4 = kD * kD / 4;
  const int i = blockIdx.x * blockDim.x + threadIdx.x;
  const int y = blockIdx.y;
  const float* src;
  unsigned short* dst;
  float s = 1.0f;
  if (y < 2) {
    src = x + (size_t)y * n4 * 4;
    dst = xb + (size_t)y * n4 * 4;
  } else {
    src = (y == 2) ? wq : (y == 3) ? wk : (y == 4) ? wv : wo;
    dst = wqkv + (size_t)(y - 2) * n4 * 4;
    if (y == 2) s = 0.08838834764831845f * 1.44269504088896340736f;
  }
  float4 v = ((const float4*)src)[i];
  ushort4 o;
  o.x = f2bf(v.x * s); o.y = f2bf(v.y * s); o.z = f2bf(v.z * s); o.w = f2bf(v.w * s);
  ((ushort4*)dst)[i] = o;
}

// ---------------- fused QKV GEMM with routing epilogue ----------------
// 128x128 tile, BK=64, single-buffer, 2 blocks/CU. LDS rows of 64 elems
// (8 x 16B chunks); chunk swizzle ^(row&7): conflict-free ds_read_b128 +
// coalesced staging via pre-swizzled global source (rule 21 both-sides).
__global__ __launch_bounds__(256, 2) void gemm_qkv(
    const unsigned short* __restrict__ A, const unsigned short* __restrict__ W,
    unsigned short* __restrict__ Qb, unsigned short* __restrict__ Kb,
    unsigned short* __restrict__ Vt) {
  constexpr int K = 2048;
  __shared__ unsigned short Asm[128 * 64];
  __shared__ unsigned short Bsm[128 * 64];
  const int t = threadIdx.x;
  const int wave = t >> 6, lane = t & 63;
  const int ln = lane & 15, quad = lane >> 4;
  const int wr = wave >> 1, wc = wave & 1;
  const int m0 = blockIdx.y * 128, n0 = blockIdx.x * 128;

  const int srow = t >> 3;
  const int scol = ((t & 7) ^ (srow & 7)) << 3;
  const unsigned short* gA = A + (size_t)(m0 + srow) * K + scol;
  const unsigned short* gW = W + (size_t)(n0 + srow) * K + scol;
  const size_t g32 = (size_t)32 * K;
  unsigned short* lA = Asm + wave * 512;
  unsigned short* lB = Bsm + wave * 512;

  f32x4 acc[4][4] = {};

  for (int k0 = 0; k0 < K; k0 += 64) {
    __syncthreads();
#pragma unroll
    for (int i = 0; i < 4; ++i) {
      gld_lds16(gA + i * g32, lA + i * 2048);
      gld_lds16(gW + i * g32, lB + i * 2048);
    }
    gA += 64; gW += 64;
    __syncthreads();

#pragma unroll
    for (int kk = 0; kk < 2; ++kk) {
      bf16x8 af[4], bw[4];
#pragma unroll
      for (int mt = 0; mt < 4; ++mt) {
        const int row = wr * 64 + mt * 16 + ln;
        af[mt] = *(const bf16x8*)(Asm + row * 64 +
                                  (((kk * 4 + quad) ^ (row & 7)) << 3));
      }
#pragma unroll
      for (int nt = 0; nt < 4; ++nt) {
        const int row = wc * 64 + nt * 16 + ln;
        bw[nt] = *(const bf16x8*)(Bsm + row * 64 +
                                  (((kk * 4 + quad) ^ (row & 7)) << 3));
      }
#pragma unroll
      for (int mt = 0; mt < 4; ++mt)
#pragma unroll
        for (int nt = 0; nt < 4; ++nt)
          acc[mt][nt] = __builtin_amdgcn_mfma_f32_16x16x32_bf16(
              af[mt], bw[nt], acc[mt][nt], 0, 0, 0);
    }
  }

  const int cm = m0 + wr * 64 + quad * 4;
  const int cn = n0 + wc * 64 + ln;
  if (n0 < 4096) {
    unsigned short* dst = (n0 < 2048) ? Qb : Kb;
    const int cnl = cn & 2047;
#pragma unroll
    for (int mt = 0; mt < 4; ++mt)
#pragma unroll
      for (int r = 0; r < 4; ++r) {
        const size_t rowoff = (size_t)(cm + mt * 16 + r) * kD + cnl;
#pragma unroll
        for (int nt = 0; nt < 4; ++nt) dst[rowoff + nt * 16] = f2bf(acc[mt][nt][r]);
      }
  } else {
    // V transpose epilogue: the 4 r-values of one (mt,nt) frag are
    // s-consecutive (cm % 4 == 0, same 2048-row block) -> one ushort4 store.
#pragma unroll
    for (int mt = 0; mt < 4; ++mt) {
      const int m = cm + mt * 16;  // r = 0 base; m % 4 == 0
      const int bb = m >> 11, s = m & 2047;
#pragma unroll
      for (int nt = 0; nt < 4; ++nt) {
        const int d = cn + nt * 16 - 4096;
        ushort4 pk;
        pk.x = f2bf(acc[mt][nt][0]);
        pk.y = f2bf(acc[mt][nt][1]);
        pk.z = f2bf(acc[mt][nt][2]);
        pk.w = f2bf(acc[mt][nt][3]);
        *(ushort4*)&Vt[((size_t)(bb * 2048 + d)) * (size_t)kS + s] = pk;
      }
    }
  }
}

// ---------------- generic C[M,N] = A[M,K] @ W[N,K]^T ----------------
// 128x128 tile, BK=64, single-buffer (R4 structure). LDS rows of 64 elems
// (8 x 16B chunks); chunk swizzle ^(row&7): conflict-free ds_read_b128 +
// coalesced staging.
template <bool OUT_BF16>
__global__ __launch_bounds__(256, 2) void gemm_bt(
    const unsigned short* __restrict__ A, const unsigned short* __restrict__ W,
    void* __restrict__ C, int M, int N, int K) {
  __shared__ unsigned short Asm[128 * 64];
  __shared__ unsigned short Bsm[128 * 64];
  const int t = threadIdx.x;
  const int wave = t >> 6, lane = t & 63;
  const int ln = lane & 15, quad = lane >> 4;
  const int wr = wave >> 1, wc = wave & 1;
  const int m0 = blockIdx.y * 128, n0 = blockIdx.x * 128;

  const int srow = t >> 3;
  const int scol = ((t & 7) ^ (srow & 7)) << 3;
  const unsigned short* gA = A + (size_t)(m0 + srow) * K + scol;
  const unsigned short* gW = W + (size_t)(n0 + srow) * K + scol;
  const size_t g32 = (size_t)32 * K;
  unsigned short* lA = Asm + wave * 512;
  unsigned short* lB = Bsm + wave * 512;

  f32x4 acc[4][4] = {};

  for (int k0 = 0; k0 < K; k0 += 64) {
    __syncthreads();
#pragma unroll
    for (int i = 0; i < 4; ++i) {
      gld_lds16(gA + i * g32, lA + i * 2048);
      gld_lds16(gW + i * g32, lB + i * 2048);
    }
    gA += 64; gW += 64;
    __syncthreads();

#pragma unroll
    for (int kk = 0; kk < 2; ++kk) {
      bf16x8 af[4], bw[4];
#pragma unroll
      for (int mt = 0; mt < 4; ++mt) {
        const int row = wr * 64 + mt * 16 + ln;
        af[mt] = *(const bf16x8*)(Asm + row * 64 +
                                  (((kk * 4 + quad) ^ (row & 7)) << 3));
      }
#pragma unroll
      for (int nt = 0; nt < 4; ++nt) {
        const int row = wc * 64 + nt * 16 + ln;
        bw[nt] = *(const bf16x8*)(Bsm + row * 64 +
                                  (((kk * 4 + quad) ^ (row & 7)) << 3));
      }
#pragma unroll
      for (int mt = 0; mt < 4; ++mt)
#pragma unroll
        for (int nt = 0; nt < 4; ++nt)
          acc[mt][nt] = __builtin_amdgcn_mfma_f32_16x16x32_bf16(
              af[mt], bw[nt], acc[mt][nt], 0, 0, 0);
    }
  }

  const int cm = m0 + wr * 64 + quad * 4;
  const int cn = n0 + wc * 64 + ln;
#pragma unroll
  for (int mt = 0; mt < 4; ++mt)
#pragma unroll
    for (int r = 0; r < 4; ++r) {
      const size_t rowoff = (size_t)(cm + mt * 16 + r) * N + cn;
      if (OUT_BF16) {
        unsigned short* Cb = (unsigned short*)C;
#pragma unroll
        for (int nt = 0; nt < 4; ++nt) Cb[rowoff + nt * 16] = f2bf(acc[mt][nt][r]);
      } else {
        float* Cf = (float*)C;
#pragma unroll
        for (int nt = 0; nt < 4; ++nt) Cf[rowoff + nt * 16] = acc[mt][nt][r];
      }
    }
}

// ---------------- causal flash attention (S^T, kv-split, K/V dbuf) --------
// One block per (b, h, chunk); chunks as in R6 (light qt<8 full-range ->
// direct bf16; heavy qt>=8 two kv-halves -> additive f32 partials). R7:
// K/V double-buffered (80KB LDS, 2 blocks/CU). Per iter: issue stage(it+1)
// into buf^1; vmcnt(8) waits only for the PREVIOUS iter's 8 loads (stage
// latency hidden under an entire iteration); barrier; compute(buf);
// lgkmcnt(0)+barrier (all ds_reads of buf processed before any wave's next
// stage may overwrite it); flip. Last iter peeled to vmcnt(0).
__global__ __launch_bounds__(256, 2) void flash_attn(
    const unsigned short* __restrict__ Q, const unsigned short* __restrict__ Kb,
    const unsigned short* __restrict__ Vt, unsigned short* __restrict__ Ob,
    float* __restrict__ Op, float* __restrict__ Lp) {
  __shared__ unsigned short Ksm[2][64 * 128];
  __shared__ unsigned short Vsm[2][128 * 64];
  __shared__ unsigned short Psm[4][2048];  // per wave: 32 q x 64 kv
  const int t = threadIdx.x;
  const int wave = t >> 6, lane = t & 63;
  const int ln = lane & 15, quad = lane >> 4;
  const int bx = blockIdx.x;
  const int bh = bx & 31, b = bh >> 4, h = bh & 15;
  const int cid = bx >> 5;

  int qt, it0, it1, pc;
  bool heavy;
  if (cid < 8) {
    qt = cid; it0 = 0; it1 = 2 * qt + 2; heavy = false; pc = 0;
  } else {
    const int c = cid - 8;
    qt = 8 + (c >> 1);
    const int half = c & 1;
    it0 = half ? (qt + 1) : 0;
    it1 = half ? (2 * qt + 2) : (qt + 1);
    heavy = true;
    pc = (bh * 8 + (qt - 8)) * 2 + half;
  }
  const int q0 = qt << 7;

  bf16x8 qf[2][4];
#pragma unroll
  for (int st = 0; st < 2; ++st) {
    const size_t qoff =
        ((size_t)(b * kS + q0 + st * 64 + wave * 16 + ln)) * kD + h * kHD;
#pragma unroll
    for (int ks = 0; ks < 4; ++ks)
      qf[st][ks] = *(const bf16x8*)(Q + qoff + ks * 32 + quad * 8);
  }

  float lsum[2] = {0.0f, 0.0f};  // per-lane partial row-sum for q = ln
  f32x4 oa[2][8] = {};

  const int krow = t >> 4;
  const unsigned short* gK =
      Kb + ((size_t)(b * kS) + krow) * kD + h * kHD + (((t & 15) ^ krow) << 3);
  const int vrow = t >> 3;
  const unsigned short* gV =
      Vt + ((size_t)(bh * 128 + vrow)) * kS + (((t & 7) ^ (vrow & 7)) << 3);

#define ATT_STAGE(IT, BUF)                                                     \
  {                                                                            \
    const int kvs_ = (IT) << 6;                                                \
    _Pragma("unroll") for (int i = 0; i < 4; ++i)                              \
      gld_lds16(gK + ((size_t)kvs_ + i * 16) * kD,                             \
                &Ksm[BUF][0] + i * 2048 + wave * 512);                         \
    _Pragma("unroll") for (int i = 0; i < 4; ++i)                              \
      gld_lds16(gV + (size_t)i * 32 * kS + kvs_,                               \
                &Vsm[BUF][0] + i * 2048 + wave * 512);                         \
  }

  ATT_STAGE(it0, 0);
  int buf = 0;

  for (int it = it0; it < it1; ++it) {
    const int kv0 = it << 6;
    if (it + 1 < it1) {
      ATT_STAGE(it + 1, buf ^ 1);
      asm volatile("s_waitcnt vmcnt(8)" ::: "memory");
    } else {
      asm volatile("s_waitcnt vmcnt(0)" ::: "memory");
    }
    __builtin_amdgcn_s_barrier();
    asm volatile("" ::: "memory");

    const unsigned short* Kc = &Ksm[buf][0];
    const unsigned short* Vc = &Vsm[buf][0];

    // S^T[kv][q]: A = K-frag, B = Q-frag (swapped order)
    f32x4 sc[2][4] = {};
#pragma unroll
    for (int ct = 0; ct < 4; ++ct) {
      const int row = ct * 16 + ln;
#pragma unroll
      for (int ks = 0; ks < 4; ++ks) {
        bf16x8 kf =
            *(const bf16x8*)(Kc + row * 128 + (((ks * 4 + quad) ^ ln) << 3));
#pragma unroll
        for (int st = 0; st < 2; ++st)
          sc[st][ct] = __builtin_amdgcn_mfma_f32_16x16x32_bf16(
              kf, qf[st][ks], sc[st][ct], 0, 0, 0);
      }
    }

    // lane holds S^T[kv = ct*16+quad*4+r][q = ln]; mask, exp2, pack, b64 write
#pragma unroll
    for (int st = 0; st < 2; ++st) {
      const int q_lo = q0 + st * 64 + wave * 16;
      const bool full = (kv0 + 63 <= q_lo);  // wave-uniform
      const int qs = q_lo + ln;
      float ls = 0.0f;
#pragma unroll
      for (int ct = 0; ct < 4; ++ct) {
        const int kvb = kv0 + ct * 16 + quad * 4;
        float p[4];
#pragma unroll
        for (int r = 0; r < 4; ++r) {
          float s = sc[st][ct][r];
          if (!full && (kvb + r > qs)) s = -1e30f;
          p[r] = exp2f(s);
          ls += p[r];
        }
        const uint32_t u0 = (uint32_t)f2bf(p[0]) | ((uint32_t)f2bf(p[1]) << 16);
        const uint32_t u1 = (uint32_t)f2bf(p[2]) | ((uint32_t)f2bf(p[3]) << 16);
        const int cs = (ct * 4 + quad) ^ (ln & 14);  // 4-elem chunk swizzle
        uint2 u; u.x = u0; u.y = u1;
        *(uint2*)(&Psm[wave][(st * 16 + ln) * 64 + cs * 4]) = u;
      }
      lsum[st] += ls;
    }

    // PV: pf = P A-frag (kv-contiguous b128), vf as before; each feeds 2 MFMAs
    bf16x8 pf[2][2];
#pragma unroll
    for (int st = 0; st < 2; ++st)
#pragma unroll
      for (int ks = 0; ks < 2; ++ks)
        pf[st][ks] = *(const bf16x8*)(
            &Psm[wave][(st * 16 + ln) * 64 +
                       (((ks * 8 + quad * 2) ^ (ln & 14)) << 2)]);
#pragma unroll
    for (int ct = 0; ct < 8; ++ct) {
      const int row = ct * 16 + ln;
#pragma unroll
      for (int ks = 0; ks < 2; ++ks) {
        bf16x8 vf =
            *(const bf16x8*)(Vc + row * 64 + (((ks * 4 + quad) ^ (ln & 7)) << 3));
#pragma unroll
        for (int st = 0; st < 2; ++st)
          oa[st][ct] = __builtin_amdgcn_mfma_f32_16x16x32_bf16(
              pf[st][ks], vf, oa[st][ct], 0, 0, 0);
      }
    }

    // write-after-read fence: this wave's ds_reads of buf fully processed
    // (lgkmcnt(0)) before any wave crossing the barrier can stage into it.
    asm volatile("s_waitcnt lgkmcnt(0)" ::: "memory");
    __builtin_amdgcn_s_barrier();
    asm volatile("" ::: "memory");
    buf ^= 1;
  }
#undef ATT_STAGE

  // epilogue: reduce row sums; light -> normalized bf16; heavy -> f32 partial
#pragma unroll
  for (int st = 0; st < 2; ++st) {
    float l = lsum[st];
    l += __shfl_xor(l, 16, 64);
    l += __shfl_xor(l, 32, 64);  // now every lane has total for q = its ln
    if (!heavy) {
      float inv[4];
#pragma unroll
      for (int r = 0; r < 4; ++r)
        inv[r] = 1.0f / __shfl(l, (lane & 48) | (quad * 4 + r), 64);
#pragma unroll
      for (int r = 0; r < 4; ++r) {
        const size_t orow =
            ((size_t)(b * kS + q0 + st * 64 + wave * 16 + quad * 4 + r)) * kD +
            h * kHD + ln;
#pragma unroll
        for (int ct = 0; ct < 8; ++ct)
          Ob[orow + ct * 16] = f2bf(oa[st][ct][r] * inv[r]);
      }
    } else {
      if (quad == 0) Lp[pc * 128 + st * 64 + wave * 16 + ln] = l;
#pragma unroll
      for (int r = 0; r < 4; ++r) {
        const int row = st * 64 + wave * 16 + quad * 4 + r;
        float* dst = Op + (size_t)pc * 16384 + row * 128 + ln;
#pragma unroll
        for (int ct = 0; ct < 8; ++ct) dst[ct * 16] = oa[st][ct][r];
      }
    }
  }
}

// ---------------- combine kv-split halves (heavy q-tiles only) ------------
// One block per p = (bh*8 + qt-8); sums the two unnormalized f32 partials
// and normalizes by (la+lb). 42MB traffic, memory-bound.
__global__ __launch_bounds__(256) void attn_combine(
    const float* __restrict__ Op, const float* __restrict__ Lp,
    unsigned short* __restrict__ Ob) {
  const int p = blockIdx.x;
  const int bh = p >> 3, qt = 8 + (p & 7);
  const int b = bh >> 4, h = bh & 15;
  const int q0 = qt << 7;
  const float* Oa = Op + (size_t)(p * 2 + 0) * 16384;
  const float* Obp = Op + (size_t)(p * 2 + 1) * 16384;
  const float* La = Lp + (p * 2 + 0) * 128;
  const float* Lb = Lp + (p * 2 + 1) * 128;
#pragma unroll
  for (int i = 0; i < 16; ++i) {
    const int e = (i * 256 + threadIdx.x) * 4;  // float4 index
    const int row = e >> 7, d = e & 127;
    const float4 a = *(const float4*)(Oa + e);
    const float4 bv = *(const float4*)(Obp + e);
    const float inv = 1.0f / (La[row] + Lb[row]);
    ushort4 o;
    o.x = f2bf((a.x + bv.x) * inv);
    o.y = f2bf((a.y + bv.y) * inv);
    o.z = f2bf((a.z + bv.z) * inv);
    o.w = f2bf((a.w + bv.w) * inv);
    *(ushort4*)&Ob[((size_t)(b * kS + q0 + row)) * kD + h * kHD + d] = o;
  }
}

}  // namespace

extern "C" void kernel_launch(void* const* d_in, const int* in_sizes, int n_in,
                              void* d_out, int out_size, void* d_ws, size_t ws_size,
                              hipStream_t stream) {
  (void)in_sizes; (void)n_in; (void)out_size; (void)ws_size;
  const float* x  = (const float*)d_in[0];
  const float* wq = (const float*)d_in[3];
  const float* wk = (const float*)d_in[4];
  const float* wv = (const float*)d_in[5];
  const float* wo = (const float*)d_in[6];
  float* out = (float*)d_out;

  unsigned short* ws   = (unsigned short*)d_ws;
  unsigned short* xb   = ws;
  unsigned short* wqkv = xb + (size_t)kM * kD;   // wq,wk,wv,wo contiguous
  unsigned short* wob  = wqkv + 3 * (size_t)kD * kD;
  unsigned short* Qb   = wob + (size_t)kD * kD;
  unsigned short* Kbuf = Qb  + (size_t)kM * kD;
  unsigned short* Vt   = Kbuf + (size_t)kM * kD;  // [b*2048+d][2048]
  unsigned short* Ab   = Vt + (size_t)kM * kD;

  // kv-split partials overlay xb + wq/wk planes (dead after gemm_qkv):
  // Op 512*16384 f32 = 33.55MB + Lp 256KB < 41.9MB dead region (wob safe).
  float* Op = (float*)d_ws;
  float* Lp = Op + (size_t)512 * 16384;

  const int n4 = kD * kD / 4;
  cvt_all<<<dim3(n4 / 256, 6), 256, 0, stream>>>(x, wq, wk, wv, wo, xb, wqkv);

  gemm_qkv<<<dim3(6144 / 128, kM / 128), 256, 0, stream>>>(xb, wqkv, Qb, Kbuf, Vt);

  flash_attn<<<dim3(768), 256, 0, stream>>>(Qb, Kbuf, Vt, Ab, Op, Lp);

  attn_combine<<<dim3(256), 256, 0, stream>>>(Op, Lp, Ab);

  gemm_bt<false><<<dim3(kD / 128, kM / 128), 256, 0, stream>>>(Ab, wob, out, kM, kD, kD);
}

// Round 9
// 358.776 us; speedup vs baseline: 1.0490x; 1.0490x over previous
//
#include <hip/hip_runtime.h>
#include <hip/hip_bf16.h>
#include <stdint.h>

// Attention layer, MI355X. RoPE is a no-op, mask is exactly causal.
// cvt fp32->bf16 (scale*log2e folded into wq; grid-stride 8xfloat4/thread —
// 24576 tiny blocks were dispatch-bound); fused QKV GEMM (V written
// transposed) at the proven R4 structure (128x128, BK=64, single-buffer,
// 2 blocks/CU); causal flash attention: contiguous 128-row q-blocks,
// KV-SPLIT load balance (qt>=8 tiles run as two kv-halves writing additive
// f32 partials; attn_combine normalizes; max serial depth 16, 768 blocks,
// 48KB LDS -> 3 blocks/CU — the R7 K/V dbuf cost 3->2 blocks/CU and
// regressed +15us; occupancy beats intra-block pipelining here, 3rd
// confirmation). Out-proj GEMM same R4 structure.
// (R8 resubmit: container-level infra failure, kernel never measured.)

namespace {

constexpr int kB = 2;
constexpr int kS = 2048;
constexpr int kD = 2048;
constexpr int kH = 16;
constexpr int kHD = 128;
constexpr int kM = kB * kS;  // 4096 token rows

typedef __attribute__((ext_vector_type(8))) __bf16 bf16x8;
typedef __attribute__((ext_vector_type(4))) float f32x4;

__device__ __forceinline__ unsigned short f2bf(float x) {
  uint32_t u = __float_as_uint(x);
  u += 0x7fffu + ((u >> 16) & 1u);
  return (unsigned short)(u >> 16);
}

__device__ __forceinline__ void gld_lds16(const void* g, void* l) {
  __builtin_amdgcn_global_load_lds((__attribute__((address_space(1))) void*)g,
                                   (__attribute__((address_space(3))) void*)l,
                                   16, 0, 0);
}

// ---------------- all fp32 -> bf16 casts, one dispatch ----------------
// 8 float4 per thread, coalesced stride loop: 3072 blocks of 32KB each
// (was 24576 blocks x 4KB -> dispatch-rate bound).
__global__ void cvt_all(const float* __restrict__ x, const float* __restrict__ wq,
                        const float* __restrict__ wk, const float* __restrict__ wv,
                        const float* __restrict__ wo, unsigned short* __restrict__ xb,
                        unsigned short* __restrict__ wqkv) {
  constexpr int n4 = kD * kD / 4;  // float4 count per plane
  const int y = blockIdx.y;
  const float* src;
  unsigned short* dst;
  float s = 1.0f;
  if (y < 2) {
    src = x + (size_t)y * n4 * 4;
    dst = xb + (size_t)y * n4 * 4;
  } else {
    src = (y == 2) ? wq : (y == 3) ? wk : (y == 4) ? wv : wo;
    dst = wqkv + (size_t)(y - 2) * n4 * 4;
    if (y == 2) s = 0.08838834764831845f * 1.44269504088896340736f;
  }
  const int base = blockIdx.x * 256 + threadIdx.x;
#pragma unroll
  for (int j = 0; j < 8; ++j) {
    const int i = j * (512 * 256) + base;  // 512 x-blocks x 256 thr x 8 = n4
    float4 v = ((const float4*)src)[i];
    ushort4 o;
    o.x = f2bf(v.x * s); o.y = f2bf(v.y * s);
    o.z = f2bf(v.z * s); o.w = f2bf(v.w * s);
    ((ushort4*)dst)[i] = o;
  }
}

// ---------------- fused QKV GEMM with routing epilogue ----------------
// 128x128 tile, BK=64, single-buffer, 2 blocks/CU. LDS rows of 64 elems
// (8 x 16B chunks); chunk swizzle ^(row&7): conflict-free ds_read_b128 +
// coalesced staging via pre-swizzled global source (rule 21 both-sides).
__global__ __launch_bounds__(256, 2) void gemm_qkv(
    const unsigned short* __restrict__ A, const unsigned short* __restrict__ W,
    unsigned short* __restrict__ Qb, unsigned short* __restrict__ Kb,
    unsigned short* __restrict__ Vt) {
  constexpr int K = 2048;
  __shared__ unsigned short Asm[128 * 64];
  __shared__ unsigned short Bsm[128 * 64];
  const int t = threadIdx.x;
  const int wave = t >> 6, lane = t & 63;
  const int ln = lane & 15, quad = lane >> 4;
  const int wr = wave >> 1, wc = wave & 1;
  const int m0 = blockIdx.y * 128, n0 = blockIdx.x * 128;

  const int srow = t >> 3;
  const int scol = ((t & 7) ^ (srow & 7)) << 3;
  const unsigned short* gA = A + (size_t)(m0 + srow) * K + scol;
  const unsigned short* gW = W + (size_t)(n0 + srow) * K + scol;
  const size_t g32 = (size_t)32 * K;
  unsigned short* lA = Asm + wave * 512;
  unsigned short* lB = Bsm + wave * 512;

  f32x4 acc[4][4] = {};

  for (int k0 = 0; k0 < K; k0 += 64) {
    __syncthreads();
#pragma unroll
    for (int i = 0; i < 4; ++i) {
      gld_lds16(gA + i * g32, lA + i * 2048);
      gld_lds16(gW + i * g32, lB + i * 2048);
    }
    gA += 64; gW += 64;
    __syncthreads();

#pragma unroll
    for (int kk = 0; kk < 2; ++kk) {
      bf16x8 af[4], bw[4];
#pragma unroll
      for (int mt = 0; mt < 4; ++mt) {
        const int row = wr * 64 + mt * 16 + ln;
        af[mt] = *(const bf16x8*)(Asm + row * 64 +
                                  (((kk * 4 + quad) ^ (row & 7)) << 3));
      }
#pragma unroll
      for (int nt = 0; nt < 4; ++nt) {
        const int row = wc * 64 + nt * 16 + ln;
        bw[nt] = *(const bf16x8*)(Bsm + row * 64 +
                                  (((kk * 4 + quad) ^ (row & 7)) << 3));
      }
#pragma unroll
      for (int mt = 0; mt < 4; ++mt)
#pragma unroll
        for (int nt = 0; nt < 4; ++nt)
          acc[mt][nt] = __builtin_amdgcn_mfma_f32_16x16x32_bf16(
              af[mt], bw[nt], acc[mt][nt], 0, 0, 0);
    }
  }

  const int cm = m0 + wr * 64 + quad * 4;
  const int cn = n0 + wc * 64 + ln;
  if (n0 < 4096) {
    unsigned short* dst = (n0 < 2048) ? Qb : Kb;
    const int cnl = cn & 2047;
#pragma unroll
    for (int mt = 0; mt < 4; ++mt)
#pragma unroll
      for (int r = 0; r < 4; ++r) {
        const size_t rowoff = (size_t)(cm + mt * 16 + r) * kD + cnl;
#pragma unroll
        for (int nt = 0; nt < 4; ++nt) dst[rowoff + nt * 16] = f2bf(acc[mt][nt][r]);
      }
  } else {
    // V transpose epilogue: the 4 r-values of one (mt,nt) frag are
    // s-consecutive (cm % 4 == 0, same 2048-row block) -> one ushort4 store.
#pragma unroll
    for (int mt = 0; mt < 4; ++mt) {
      const int m = cm + mt * 16;  // r = 0 base; m % 4 == 0
      const int bb = m >> 11, s = m & 2047;
#pragma unroll
      for (int nt = 0; nt < 4; ++nt) {
        const int d = cn + nt * 16 - 4096;
        ushort4 pk;
        pk.x = f2bf(acc[mt][nt][0]);
        pk.y = f2bf(acc[mt][nt][1]);
        pk.z = f2bf(acc[mt][nt][2]);
        pk.w = f2bf(acc[mt][nt][3]);
        *(ushort4*)&Vt[((size_t)(bb * 2048 + d)) * (size_t)kS + s] = pk;
      }
    }
  }
}

// ---------------- generic C[M,N] = A[M,K] @ W[N,K]^T ----------------
// 128x128 tile, BK=64, single-buffer (R4 structure). LDS rows of 64 elems
// (8 x 16B chunks); chunk swizzle ^(row&7): conflict-free ds_read_b128 +
// coalesced staging.
template <bool OUT_BF16>
__global__ __launch_bounds__(256, 2) void gemm_bt(
    const unsigned short* __restrict__ A, const unsigned short* __restrict__ W,
    void* __restrict__ C, int M, int N, int K) {
  __shared__ unsigned short Asm[128 * 64];
  __shared__ unsigned short Bsm[128 * 64];
  const int t = threadIdx.x;
  const int wave = t >> 6, lane = t & 63;
  const int ln = lane & 15, quad = lane >> 4;
  const int wr = wave >> 1, wc = wave & 1;
  const int m0 = blockIdx.y * 128, n0 = blockIdx.x * 128;

  const int srow = t >> 3;
  const int scol = ((t & 7) ^ (srow & 7)) << 3;
  const unsigned short* gA = A + (size_t)(m0 + srow) * K + scol;
  const unsigned short* gW = W + (size_t)(n0 + srow) * K + scol;
  const size_t g32 = (size_t)32 * K;
  unsigned short* lA = Asm + wave * 512;
  unsigned short* lB = Bsm + wave * 512;

  f32x4 acc[4][4] = {};

  for (int k0 = 0; k0 < K; k0 += 64) {
    __syncthreads();
#pragma unroll
    for (int i = 0; i < 4; ++i) {
      gld_lds16(gA + i * g32, lA + i * 2048);
      gld_lds16(gW + i * g32, lB + i * 2048);
    }
    gA += 64; gW += 64;
    __syncthreads();

#pragma unroll
    for (int kk = 0; kk < 2; ++kk) {
      bf16x8 af[4], bw[4];
#pragma unroll
      for (int mt = 0; mt < 4; ++mt) {
        const int row = wr * 64 + mt * 16 + ln;
        af[mt] = *(const bf16x8*)(Asm + row * 64 +
                                  (((kk * 4 + quad) ^ (row & 7)) << 3));
      }
#pragma unroll
      for (int nt = 0; nt < 4; ++nt) {
        const int row = wc * 64 + nt * 16 + ln;
        bw[nt] = *(const bf16x8*)(Bsm + row * 64 +
                                  (((kk * 4 + quad) ^ (row & 7)) << 3));
      }
#pragma unroll
      for (int mt = 0; mt < 4; ++mt)
#pragma unroll
        for (int nt = 0; nt < 4; ++nt)
          acc[mt][nt] = __builtin_amdgcn_mfma_f32_16x16x32_bf16(
              af[mt], bw[nt], acc[mt][nt], 0, 0, 0);
    }
  }

  const int cm = m0 + wr * 64 + quad * 4;
  const int cn = n0 + wc * 64 + ln;
#pragma unroll
  for (int mt = 0; mt < 4; ++mt)
#pragma unroll
    for (int r = 0; r < 4; ++r) {
      const size_t rowoff = (size_t)(cm + mt * 16 + r) * N + cn;
      if (OUT_BF16) {
        unsigned short* Cb = (unsigned short*)C;
#pragma unroll
        for (int nt = 0; nt < 4; ++nt) Cb[rowoff + nt * 16] = f2bf(acc[mt][nt][r]);
      } else {
        float* Cf = (float*)C;
#pragma unroll
        for (int nt = 0; nt < 4; ++nt) Cf[rowoff + nt * 16] = acc[mt][nt][r];
      }
    }
}

// ---------------- causal flash attention (S^T layout, kv-split) ----------
// One block per (b, h, chunk). Chunks: qt<8 -> full kv range [0, 2qt+2)
// (light, direct bf16 write); qt>=8 -> two chunks [0,qt+1) / [qt+1,2qt+2)
// (heavy, unnormalized f32 O partial + row-sum to workspace; no-max exp2
// softmax makes halves exactly additive). Total staged kv-iters unchanged
// (272/bh); max serial depth 16; 768 blocks = 3/CU co-resident (48KB LDS).
// Inner loop: S^T = K.Q^T swapped-operand QK^T; P packed to Psm as b64.
__global__ __launch_bounds__(256, 3) void flash_attn(
    const unsigned short* __restrict__ Q, const unsigned short* __restrict__ Kb,
    const unsigned short* __restrict__ Vt, unsigned short* __restrict__ Ob,
    float* __restrict__ Op, float* __restrict__ Lp) {
  __shared__ unsigned short Ksm[64 * 128];
  __shared__ unsigned short Vsm[128 * 64];
  __shared__ unsigned short Psm[4][2048];  // per wave: 32 q x 64 kv
  const int t = threadIdx.x;
  const int wave = t >> 6, lane = t & 63;
  const int ln = lane & 15, quad = lane >> 4;
  const int bx = blockIdx.x;
  const int bh = bx & 31, b = bh >> 4, h = bh & 15;
  const int cid = bx >> 5;

  int qt, it0, it1, pc;
  bool heavy;
  if (cid < 8) {
    qt = cid; it0 = 0; it1 = 2 * qt + 2; heavy = false; pc = 0;
  } else {
    const int c = cid - 8;
    qt = 8 + (c >> 1);
    const int half = c & 1;
    it0 = half ? (qt + 1) : 0;
    it1 = half ? (2 * qt + 2) : (qt + 1);
    heavy = true;
    pc = (bh * 8 + (qt - 8)) * 2 + half;
  }
  const int q0 = qt << 7;

  bf16x8 qf[2][4];
#pragma unroll
  for (int st = 0; st < 2; ++st) {
    const size_t qoff =
        ((size_t)(b * kS + q0 + st * 64 + wave * 16 + ln)) * kD + h * kHD;
#pragma unroll
    for (int ks = 0; ks < 4; ++ks)
      qf[st][ks] = *(const bf16x8*)(Q + qoff + ks * 32 + quad * 8);
  }

  float lsum[2] = {0.0f, 0.0f};  // per-lane partial row-sum for q = ln
  f32x4 oa[2][8] = {};

  const int krow = t >> 4;
  const unsigned short* gK =
      Kb + ((size_t)(b * kS) + krow) * kD + h * kHD + (((t & 15) ^ krow) << 3);
  const int vrow = t >> 3;
  const unsigned short* gV =
      Vt + ((size_t)(bh * 128 + vrow)) * kS + (((t & 7) ^ (vrow & 7)) << 3);

  for (int it = it0; it < it1; ++it) {
    const int kv0 = it << 6;
    __syncthreads();  // prev-iter LDS reads done
#pragma unroll
    for (int i = 0; i < 4; ++i)
      gld_lds16(gK + ((size_t)kv0 + i * 16) * kD, Ksm + i * 2048 + wave * 512);
#pragma unroll
    for (int i = 0; i < 4; ++i)
      gld_lds16(gV + (size_t)i * 32 * kS + kv0, Vsm + i * 2048 + wave * 512);
    __syncthreads();  // staging complete

    // S^T[kv][q]: A = K-frag, B = Q-frag (swapped order)
    f32x4 sc[2][4] = {};
#pragma unroll
    for (int ct = 0; ct < 4; ++ct) {
      const int row = ct * 16 + ln;
#pragma unroll
      for (int ks = 0; ks < 4; ++ks) {
        bf16x8 kf =
            *(const bf16x8*)(Ksm + row * 128 + (((ks * 4 + quad) ^ ln) << 3));
#pragma unroll
        for (int st = 0; st < 2; ++st)
          sc[st][ct] = __builtin_amdgcn_mfma_f32_16x16x32_bf16(
              kf, qf[st][ks], sc[st][ct], 0, 0, 0);
      }
    }

    // lane holds S^T[kv = ct*16+quad*4+r][q = ln]; mask, exp2, pack, b64 write
#pragma unroll
    for (int st = 0; st < 2; ++st) {
      const int q_lo = q0 + st * 64 + wave * 16;
      const bool full = (kv0 + 63 <= q_lo);  // wave-uniform
      const int qs = q_lo + ln;
      float ls = 0.0f;
#pragma unroll
      for (int ct = 0; ct < 4; ++ct) {
        const int kvb = kv0 + ct * 16 + quad * 4;
        float p[4];
#pragma unroll
        for (int r = 0; r < 4; ++r) {
          float s = sc[st][ct][r];
          if (!full && (kvb + r > qs)) s = -1e30f;
          p[r] = exp2f(s);
          ls += p[r];
        }
        const uint32_t u0 = (uint32_t)f2bf(p[0]) | ((uint32_t)f2bf(p[1]) << 16);
        const uint32_t u1 = (uint32_t)f2bf(p[2]) | ((uint32_t)f2bf(p[3]) << 16);
        const int cs = (ct * 4 + quad) ^ (ln & 14);  // 4-elem chunk swizzle
        uint2 u; u.x = u0; u.y = u1;
        *(uint2*)(&Psm[wave][(st * 16 + ln) * 64 + cs * 4]) = u;
      }
      lsum[st] += ls;
    }

    // PV: pf = P A-frag (kv-contiguous b128), vf as before; each feeds 2 MFMAs
    bf16x8 pf[2][2];
#pragma unroll
    for (int st = 0; st < 2; ++st)
#pragma unroll
      for (int ks = 0; ks < 2; ++ks)
        pf[st][ks] = *(const bf16x8*)(
            &Psm[wave][(st * 16 + ln) * 64 +
                       (((ks * 8 + quad * 2) ^ (ln & 14)) << 2)]);
#pragma unroll
    for (int ct = 0; ct < 8; ++ct) {
      const int row = ct * 16 + ln;
#pragma unroll
      for (int ks = 0; ks < 2; ++ks) {
        bf16x8 vf =
            *(const bf16x8*)(Vsm + row * 64 + (((ks * 4 + quad) ^ (ln & 7)) << 3));
#pragma unroll
        for (int st = 0; st < 2; ++st)
          oa[st][ct] = __builtin_amdgcn_mfma_f32_16x16x32_bf16(
              pf[st][ks], vf, oa[st][ct], 0, 0, 0);
      }
    }
  }

  // epilogue: reduce row sums; light -> normalized bf16; heavy -> f32 partial
#pragma unroll
  for (int st = 0; st < 2; ++st) {
    float l = lsum[st];
    l += __shfl_xor(l, 16, 64);
    l += __shfl_xor(l, 32, 64);  // now every lane has total for q = its ln
    if (!heavy) {
      float inv[4];
#pragma unroll
      for (int r = 0; r < 4; ++r)
        inv[r] = 1.0f / __shfl(l, (lane & 48) | (quad * 4 + r), 64);
#pragma unroll
      for (int r = 0; r < 4; ++r) {
        const size_t orow =
            ((size_t)(b * kS + q0 + st * 64 + wave * 16 + quad * 4 + r)) * kD +
            h * kHD + ln;
#pragma unroll
        for (int ct = 0; ct < 8; ++ct)
          Ob[orow + ct * 16] = f2bf(oa[st][ct][r] * inv[r]);
      }
    } else {
      if (quad == 0) Lp[pc * 128 + st * 64 + wave * 16 + ln] = l;
#pragma unroll
      for (int r = 0; r < 4; ++r) {
        const int row = st * 64 + wave * 16 + quad * 4 + r;
        float* dst = Op + (size_t)pc * 16384 + row * 128 + ln;
#pragma unroll
        for (int ct = 0; ct < 8; ++ct) dst[ct * 16] = oa[st][ct][r];
      }
    }
  }
}

// ---------------- combine kv-split halves (heavy q-tiles only) ------------
// One block per p = (bh*8 + qt-8); sums the two unnormalized f32 partials
// and normalizes by (la+lb). ~50MB traffic, memory-bound.
__global__ __launch_bounds__(256) void attn_combine(
    const float* __restrict__ Op, const float* __restrict__ Lp,
    unsigned short* __restrict__ Ob) {
  const int p = blockIdx.x;
  const int bh = p >> 3, qt = 8 + (p & 7);
  const int b = bh >> 4, h = bh & 15;
  const int q0 = qt << 7;
  const float* Oa = Op + (size_t)(p * 2 + 0) * 16384;
  const float* Obp = Op + (size_t)(p * 2 + 1) * 16384;
  const float* La = Lp + (p * 2 + 0) * 128;
  const float* Lb = Lp + (p * 2 + 1) * 128;
#pragma unroll
  for (int i = 0; i < 16; ++i) {
    const int e = (i * 256 + threadIdx.x) * 4;  // float4 index
    const int row = e >> 7, d = e & 127;
    const float4 a = *(const float4*)(Oa + e);
    const float4 bv = *(const float4*)(Obp + e);
    const float inv = 1.0f / (La[row] + Lb[row]);
    ushort4 o;
    o.x = f2bf((a.x + bv.x) * inv);
    o.y = f2bf((a.y + bv.y) * inv);
    o.z = f2bf((a.z + bv.z) * inv);
    o.w = f2bf((a.w + bv.w) * inv);
    *(ushort4*)&Ob[((size_t)(b * kS + q0 + row)) * kD + h * kHD + d] = o;
  }
}

}  // namespace

extern "C" void kernel_launch(void* const* d_in, const int* in_sizes, int n_in,
                              void* d_out, int out_size, void* d_ws, size_t ws_size,
                              hipStream_t stream) {
  (void)in_sizes; (void)n_in; (void)out_size; (void)ws_size;
  const float* x  = (const float*)d_in[0];
  const float* wq = (const float*)d_in[3];
  const float* wk = (const float*)d_in[4];
  const float* wv = (const float*)d_in[5];
  const float* wo = (const float*)d_in[6];
  float* out = (float*)d_out;

  unsigned short* ws   = (unsigned short*)d_ws;
  unsigned short* xb   = ws;
  unsigned short* wqkv = xb + (size_t)kM * kD;   // wq,wk,wv,wo contiguous
  unsigned short* wob  = wqkv + 3 * (size_t)kD * kD;
  unsigned short* Qb   = wob + (size_t)kD * kD;
  unsigned short* Kbuf = Qb  + (size_t)kM * kD;
  unsigned short* Vt   = Kbuf + (size_t)kM * kD;  // [b*2048+d][2048]
  unsigned short* Ab   = Vt + (size_t)kM * kD;

  // kv-split partials overlay xb + wq/wk planes (dead after gemm_qkv):
  // Op 512*16384 f32 = 33.55MB + Lp 256KB < 41.9MB dead region (wob safe).
  float* Op = (float*)d_ws;
  float* Lp = Op + (size_t)512 * 16384;

  cvt_all<<<dim3(512, 6), 256, 0, stream>>>(x, wq, wk, wv, wo, xb, wqkv);

  gemm_qkv<<<dim3(6144 / 128, kM / 128), 256, 0, stream>>>(xb, wqkv, Qb, Kbuf, Vt);

  flash_attn<<<dim3(768), 256, 0, stream>>>(Qb, Kbuf, Vt, Ab, Op, Lp);

  attn_combine<<<dim3(256), 256, 0, stream>>>(Op, Lp, Ab);

  gemm_bt<false><<<dim3(kD / 128, kM / 128), 256, 0, stream>>>(Ab, wob, out, kM, kD, kD);
}